// Round 1
// baseline (1159.515 us; speedup 1.0000x reference)
//
#include <hip/hip_runtime.h>
#include <math.h>

#define NXY 320
#define NC 20
#define NT 25
#define NPIX 102400   // 320*320

__device__ __forceinline__ float2 cmul(float2 a, float2 b) {
    return make_float2(a.x * b.x - a.y * b.y, a.x * b.y + a.y * b.x);
}

// 64-point DIF FFT (+i sign) across the 64 lanes of a wave, 5 independent
// sequences per lane. Input: v[r] = s_r[lane]. Output: v[r] = Y_r[bitrev6(lane)].
__device__ __forceinline__ void wave_fft64x5(float2 v[5]) {
    const int lane = threadIdx.x & 63;
    #pragma unroll
    for (int h = 32; h >= 1; h >>= 1) {
        const bool upper = (lane & h) != 0;
        const int i = lane & (h - 1);
        float s, c;
        __sincosf(3.14159265358979f * (float)i / (float)h, &s, &c); // e^{+i*pi*i/h} = W_{2h}^{i}
        #pragma unroll
        for (int r = 0; r < 5; ++r) {
            float ox = __shfl_xor(v[r].x, h);
            float oy = __shfl_xor(v[r].y, h);
            float2 nv;
            if (!upper) {
                nv.x = v[r].x + ox;
                nv.y = v[r].y + oy;
            } else {
                float dx = ox - v[r].x;   // x_low - x_high
                float dy = oy - v[r].y;
                nv.x = dx * c - dy * s;
                nv.y = dx * s + dy * c;
            }
            v[r] = nv;
        }
    }
}

// Full 320-point DFT (+i sign) by one wave. Input x[r] = seq[5*lane + r].
// Output: out[s] = X[J + 64*s], where J = bitrev6(lane) (returned).
__device__ __forceinline__ int wave_fft320(float2 x[5], float2 out[5]) {
    wave_fft64x5(x);
    const int lane = threadIdx.x & 63;
    const int J = (int)(__brev((unsigned)lane) >> 26);
    float2 T[5];
    T[0] = x[0];
    #pragma unroll
    for (int r = 1; r < 5; ++r) {
        float s, c;
        __sincosf(6.28318530717959f * (float)(r * J) / 320.0f, &s, &c);
        T[r] = cmul(x[r], make_float2(c, s));
    }
    const float W5x[5] = {1.0f, 0.309016994f, -0.809016994f, -0.809016994f, 0.309016994f};
    const float W5y[5] = {0.0f, 0.951056516f, 0.587785252f, -0.587785252f, -0.951056516f};
    #pragma unroll
    for (int s5 = 0; s5 < 5; ++s5) {
        float2 acc = T[0];
        #pragma unroll
        for (int r = 1; r < 5; ++r) {
            const int k = (r * s5) % 5;
            acc.x += T[r].x * W5x[k] - T[r].y * W5y[k];
            acc.y += T[r].x * W5y[k] + T[r].y * W5x[k];
        }
        out[s5] = acc;
    }
    return J;
}

// smapsC[c][p] = conj(smaps[p][c]) * (-1)^(m+n) / 320
__global__ __launch_bounds__(256) void k_prep_smaps(const float* __restrict__ smr,
                                                    const float* __restrict__ smi,
                                                    float2* __restrict__ smapsC) {
    const int p0 = blockIdx.x * 64;
    __shared__ float s_r[64 * 21];
    __shared__ float s_i[64 * 21];
    for (int j = threadIdx.x; j < 64 * NC; j += blockDim.x) {
        int p = j / NC, c = j - p * NC;
        s_r[p * 21 + c] = smr[(size_t)p0 * NC + j];
        s_i[p * 21 + c] = smi[(size_t)p0 * NC + j];
    }
    __syncthreads();
    for (int j = threadIdx.x; j < 64 * NC; j += blockDim.x) {
        int c = j >> 6, p = j & 63;
        int pg = p0 + p;
        int m = pg / NXY, n = pg - m * NXY;
        float sgn = (((m + n) & 1) ? -1.0f : 1.0f) * (1.0f / 320.0f);
        smapsC[(size_t)c * NPIX + pg] = make_float2(s_r[p * 21 + c] * sgn,
                                                    -s_i[p * 21 + c] * sgn);
    }
}

// X0[c*G+tc][p] = kspace[p][c] * mask[p][c][t0+tc] * (-1)^(m+n)
// LDS-tiled transpose: 16 pixels x (20*G) per block, coalesced read & write.
__global__ __launch_bounds__(256) void k_prep_input(const float* __restrict__ ksr,
                                                    const float* __restrict__ ksi,
                                                    const float* __restrict__ mask,
                                                    float2* __restrict__ X0,
                                                    int t0, int G) {
    const int Q = NC * G;
    const int QP = Q + 1;
    const int p0 = blockIdx.x * 16;
    __shared__ float s_mask[16 * 501];
    __shared__ float s_kr[16 * 21];
    __shared__ float s_ki[16 * 21];
    for (int j = threadIdx.x; j < 16 * NC; j += blockDim.x) {
        int p = j / NC, c = j - p * NC;
        s_kr[p * 21 + c] = ksr[(size_t)p0 * NC + j];
        s_ki[p * 21 + c] = ksi[(size_t)p0 * NC + j];
    }
    for (int j = threadIdx.x; j < 16 * Q; j += blockDim.x) {
        int p = j / Q, qq = j - p * Q;
        int c = qq / G, tc = qq - c * G;
        s_mask[p * QP + qq] =
            mask[(size_t)(p0 + p) * (NC * NT) + c * NT + (t0 + tc)];
    }
    __syncthreads();
    for (int j = threadIdx.x; j < 16 * Q; j += blockDim.x) {
        int p = j & 15, q = j >> 4;
        int c = q / G;
        int pg = p0 + p;
        int m = pg / NXY, n = pg - m * NXY;
        float sgn = ((m + n) & 1) ? -1.0f : 1.0f;
        float mk = s_mask[p * QP + q] * sgn;
        X0[(size_t)q * NPIX + pg] =
            make_float2(s_kr[p * 21 + c] * mk, s_ki[p * 21 + c] * mk);
    }
}

// Row FFTs (over n) for one (c,tc), 8 rows per block; transpose via LDS so
// Z[q][v][m] has m contiguous (64B runs).
__global__ __launch_bounds__(256) void k_fft_rows(const float2* __restrict__ X0,
                                                  float2* __restrict__ Z, int G) {
    const int mtile = blockIdx.x;   // 0..39
    const int tc = blockIdx.y;      // 0..G-1
    const int c = blockIdx.z;       // 0..19
    const int q = c * G + tc;
    const int wave = threadIdx.x >> 6;
    const int lane = threadIdx.x & 63;
    const int m0 = mtile * 8;
    __shared__ float tile[NXY * 17]; // [v][8 cplx + 1 pad]
    const float2* src = X0 + (size_t)q * NPIX;
    #pragma unroll
    for (int rnd = 0; rnd < 2; ++rnd) {
        int mm = wave + 4 * rnd;
        const float2* row = src + (size_t)(m0 + mm) * NXY + lane * 5;
        float2 x[5], out[5];
        #pragma unroll
        for (int r = 0; r < 5; ++r) x[r] = row[r];
        int J = wave_fft320(x, out);
        #pragma unroll
        for (int s5 = 0; s5 < 5; ++s5) {
            int v = J + 64 * s5;
            tile[v * 17 + mm * 2] = out[s5].x;
            tile[v * 17 + mm * 2 + 1] = out[s5].y;
        }
    }
    __syncthreads();
    float2* dst = Z + (size_t)q * NPIX + m0;
    for (int j = threadIdx.x; j < NXY * 8; j += blockDim.x) {
        int mm = j & 7, v = j >> 3;
        dst[(size_t)v * NXY + mm] =
            make_float2(tile[v * 17 + mm * 2], tile[v * 17 + mm * 2 + 1]);
    }
}

// Column FFTs (over m) + coil combine with smapsC, accumulate over c in regs.
// Block = (v-tile of 8, tc). Writes im_t[t][u][v].
__global__ __launch_bounds__(256) void k_fft_cols_combine(const float2* __restrict__ Z,
                                                          const float2* __restrict__ smapsC,
                                                          float2* __restrict__ imt,
                                                          int t0, int G) {
    const int vtile = blockIdx.x;   // 0..39
    const int tc = blockIdx.y;
    const int wave = threadIdx.x >> 6;
    const int lane = threadIdx.x & 63;
    const int v0 = vtile * 8;
    __shared__ float tile[NXY * 17];
    float2 accA[5], accB[5];
    #pragma unroll
    for (int s5 = 0; s5 < 5; ++s5) {
        accA[s5] = make_float2(0.f, 0.f);
        accB[s5] = make_float2(0.f, 0.f);
    }
    int Jsave = 0;
    for (int c = 0; c < NC; ++c) {
        const float2* zc = Z + (size_t)(c * G + tc) * NPIX;
        const float2* sc = smapsC + (size_t)c * NPIX;
        {   // v = v0 + wave
            int v = v0 + wave;
            const float2* col = zc + (size_t)v * NXY + lane * 5;
            float2 x[5], out[5];
            #pragma unroll
            for (int r = 0; r < 5; ++r) x[r] = col[r];
            int J = wave_fft320(x, out);
            Jsave = J;
            #pragma unroll
            for (int s5 = 0; s5 < 5; ++s5) {
                int u = J + 64 * s5;
                float2 t = cmul(out[s5], sc[(size_t)u * NXY + v]);
                accA[s5].x += t.x;
                accA[s5].y += t.y;
            }
        }
        {   // v = v0 + 4 + wave
            int v = v0 + 4 + wave;
            const float2* col = zc + (size_t)v * NXY + lane * 5;
            float2 x[5], out[5];
            #pragma unroll
            for (int r = 0; r < 5; ++r) x[r] = col[r];
            int J = wave_fft320(x, out);
            #pragma unroll
            for (int s5 = 0; s5 < 5; ++s5) {
                int u = J + 64 * s5;
                float2 t = cmul(out[s5], sc[(size_t)u * NXY + v]);
                accB[s5].x += t.x;
                accB[s5].y += t.y;
            }
        }
    }
    #pragma unroll
    for (int s5 = 0; s5 < 5; ++s5) {
        int u = Jsave + 64 * s5;
        int vvA = wave, vvB = 4 + wave;
        tile[u * 17 + vvA * 2] = accA[s5].x;
        tile[u * 17 + vvA * 2 + 1] = accA[s5].y;
        tile[u * 17 + vvB * 2] = accB[s5].x;
        tile[u * 17 + vvB * 2 + 1] = accB[s5].y;
    }
    __syncthreads();
    float2* dst = imt + (size_t)(t0 + tc) * NPIX + v0;
    for (int j = threadIdx.x; j < NXY * 8; j += blockDim.x) {
        int vv = j & 7, u = j >> 3;
        dst[(size_t)u * NXY + vv] =
            make_float2(tile[u * 17 + vv * 2], tile[u * 17 + vv * 2 + 1]);
    }
}

// Bilinear warp per motion state + sum over t. out = [2][320][320].
__global__ __launch_bounds__(256) void k_warp_sum(const float2* __restrict__ imt,
                                                  const float* __restrict__ flow,
                                                  float* __restrict__ out) {
    int p = blockIdx.x * blockDim.x + threadIdx.x;
    if (p >= NPIX) return;
    int x = p / NXY, y = p - x * NXY;
    float fx = (float)x, fy = (float)y;
    float ar = 0.f, ai = 0.f;
    const float* fl = flow + (size_t)p * (2 * NT);
    for (int t = 0; t < NT; ++t) {
        float u = fl[t];
        float v = fl[NT + t];
        float xs = fminf(fmaxf(fx + u, 0.0f), 319.0f);
        float ys = fminf(fmaxf(fy + v, 0.0f), 319.0f);
        float x0f = floorf(xs), y0f = floorf(ys);
        int x0 = (int)x0f, y0 = (int)y0f;
        int x1 = min(x0 + 1, NXY - 1), y1 = min(y0 + 1, NXY - 1);
        float wx = xs - x0f, wy = ys - y0f;
        const float2* base = imt + (size_t)t * NPIX;
        float2 c00 = base[x0 * NXY + y0];
        float2 c01 = base[x0 * NXY + y1];
        float2 c10 = base[x1 * NXY + y0];
        float2 c11 = base[x1 * NXY + y1];
        float w00 = (1.f - wx) * (1.f - wy), w01 = (1.f - wx) * wy;
        float w10 = wx * (1.f - wy), w11 = wx * wy;
        ar += c00.x * w00 + c01.x * w01 + c10.x * w10 + c11.x * w11;
        ai += c00.y * w00 + c01.y * w01 + c10.y * w10 + c11.y * w11;
    }
    out[p] = ar;
    out[NPIX + p] = ai;
}

extern "C" void kernel_launch(void* const* d_in, const int* in_sizes, int n_in,
                              void* d_out, int out_size, void* d_ws, size_t ws_size,
                              hipStream_t stream) {
    const float* ksr = (const float*)d_in[0];
    const float* ksi = (const float*)d_in[1];
    const float* mask = (const float*)d_in[2];
    const float* smr = (const float*)d_in[3];
    const float* smi = (const float*)d_in[4];
    const float* flow = (const float*)d_in[5];
    float* out = (float*)d_out;

    char* ws = (char*)d_ws;
    const size_t smapsC_bytes = (size_t)NC * NPIX * sizeof(float2);   // 16.4 MB
    const size_t imt_bytes = (size_t)NT * NPIX * sizeof(float2);      // 20.5 MB
    const size_t fixed = smapsC_bytes + imt_bytes;
    const size_t per_t = (size_t)2 * NC * NPIX * sizeof(float2);      // X0+Z per t: 32.8 MB

    int G = 1;
    if (ws_size > fixed + per_t) {
        size_t g = (ws_size - fixed) / per_t;
        G = (int)(g > (size_t)NT ? (size_t)NT : g);
    }
    if (G < 1) G = 1;

    float2* smapsC = (float2*)ws;
    float2* imt = (float2*)(ws + smapsC_bytes);
    float2* X0 = (float2*)(ws + fixed);
    float2* Z = (float2*)(ws + fixed + (size_t)NC * G * NPIX * sizeof(float2));

    k_prep_smaps<<<NPIX / 64, 256, 0, stream>>>(smr, smi, smapsC);
    for (int t0 = 0; t0 < NT; t0 += G) {
        int g = (NT - t0) < G ? (NT - t0) : G;
        k_prep_input<<<NPIX / 16, 256, 0, stream>>>(ksr, ksi, mask, X0, t0, g);
        k_fft_rows<<<dim3(40, g, NC), 256, 0, stream>>>(X0, Z, g);
        k_fft_cols_combine<<<dim3(40, g), 256, 0, stream>>>(Z, smapsC, imt, t0, g);
    }
    k_warp_sum<<<(NPIX + 255) / 256, 256, 0, stream>>>(imt, flow, out);
}

// Round 2
// 902.318 us; speedup vs baseline: 1.2850x; 1.2850x over previous
//
#include <hip/hip_runtime.h>
#include <hip/hip_fp16.h>
#include <math.h>

#define NXY 320
#define NC 20
#define NT 25
#define NPIX 102400   // 320*320
#define PI_F 3.14159265358979f
#define TWOPI_F 6.28318530717959f

__device__ __forceinline__ float2 cmul(float2 a, float2 b) {
    return make_float2(a.x * b.x - a.y * b.y, a.x * b.y + a.y * b.x);
}

// Per-lane FFT twiddles — invariant across every FFT a thread performs.
struct Tw {
    float2 st[6];   // stage twiddle: (1,0) for lower half, e^{+i*pi*i/h} for upper
    float  sgn[6];  // +1 lower, -1 upper
    float2 w5[5];   // w5[r] = e^{+2*pi*i * r*J / 320}
    int J;          // bitrev6(lane)
};

__device__ __forceinline__ void tw_init(Tw& t) {
    const int lane = threadIdx.x & 63;
    #pragma unroll
    for (int s = 0; s < 6; ++s) {
        const int h = 32 >> s;
        const bool up = (lane & h) != 0;
        t.sgn[s] = up ? -1.0f : 1.0f;
        if (up) {
            float ss, cc;
            __sincosf(PI_F * (float)(lane & (h - 1)) / (float)h, &ss, &cc);
            t.st[s] = make_float2(cc, ss);
        } else {
            t.st[s] = make_float2(1.0f, 0.0f);
        }
    }
    t.J = (int)(__brev((unsigned)lane) >> 26);
    t.w5[0] = make_float2(1.0f, 0.0f);
    #pragma unroll
    for (int r = 1; r < 5; ++r) {
        float ss, cc;
        __sincosf(TWOPI_F * (float)(r * t.J) / 320.0f, &ss, &cc);
        t.w5[r] = make_float2(cc, ss);
    }
}

// 320-point DFT (+i sign) by one wave; x[r] = seq[5*lane + r] in, out[s5] = X[J + 64*s5].
__device__ __forceinline__ void fft320(const Tw& t, float2 x[5], float2 out[5]) {
    #pragma unroll
    for (int s = 0; s < 6; ++s) {
        const int h = 32 >> s;
        #pragma unroll
        for (int r = 0; r < 5; ++r) {
            float ox = __shfl_xor(x[r].x, h);
            float oy = __shfl_xor(x[r].y, h);
            float dx = fmaf(t.sgn[s], x[r].x, ox);
            float dy = fmaf(t.sgn[s], x[r].y, oy);
            x[r].x = dx * t.st[s].x - dy * t.st[s].y;
            x[r].y = dx * t.st[s].y + dy * t.st[s].x;
        }
    }
    float2 T[5];
    T[0] = x[0];
    #pragma unroll
    for (int r = 1; r < 5; ++r) T[r] = cmul(x[r], t.w5[r]);
    const float W5x[5] = {1.0f, 0.309016994f, -0.809016994f, -0.809016994f, 0.309016994f};
    const float W5y[5] = {0.0f, 0.951056516f, 0.587785252f, -0.587785252f, -0.951056516f};
    #pragma unroll
    for (int s5 = 0; s5 < 5; ++s5) {
        float2 acc = T[0];
        #pragma unroll
        for (int r = 1; r < 5; ++r) {
            const int k = (r * s5) % 5;
            acc.x += T[r].x * W5x[k] - T[r].y * W5y[k];
            acc.y += T[r].x * W5y[k] + T[r].y * W5x[k];
        }
        out[s5] = acc;
    }
}

// smapsC[c][p] = conj(smaps[p][c]) * (-1)^(m+n) / 320   (fp32 staging table)
__global__ __launch_bounds__(256) void k_prep_smaps(const float* __restrict__ smr,
                                                    const float* __restrict__ smi,
                                                    float2* __restrict__ smapsC) {
    const int p0 = blockIdx.x * 64;
    __shared__ float s_r[64 * 21];
    __shared__ float s_i[64 * 21];
    for (int j = threadIdx.x; j < 64 * NC; j += blockDim.x) {
        int p = j / NC, c = j - p * NC;
        s_r[p * 21 + c] = smr[(size_t)p0 * NC + j];
        s_i[p * 21 + c] = smi[(size_t)p0 * NC + j];
    }
    __syncthreads();
    for (int j = threadIdx.x; j < 64 * NC; j += blockDim.x) {
        int c = j >> 6, p = j & 63;
        int pg = p0 + p;
        int m = pg / NXY, n = pg - m * NXY;
        float sgn = (((m + n) & 1) ? -1.0f : 1.0f) * (1.0f / 320.0f);
        smapsC[(size_t)c * NPIX + pg] = make_float2(s_r[p * 21 + c] * sgn,
                                                    -s_i[p * 21 + c] * sgn);
    }
}

// smapsP[((c*320 + v)*5 + s5)*64 + lane] = smapsC[c][(bitrev6(lane) + 64*s5)*320 + v]  (half2)
// Block: (c, s5=u-tile, v-tile of 64). Coalesced read & write via LDS.
__global__ __launch_bounds__(256) void k_perm_smaps(const float2* __restrict__ smapsC,
                                                    __half2* __restrict__ smapsP) {
    const int c = blockIdx.x;
    const int s5 = blockIdx.y;      // u0 = 64*s5
    const int v0 = blockIdx.z * 64;
    __shared__ __half2 t2[64 * 65];
    for (int j = threadIdx.x; j < 64 * 64; j += blockDim.x) {
        int ur = j >> 6, vc = j & 63;
        float2 v = smapsC[(size_t)c * NPIX + (size_t)(s5 * 64 + ur) * NXY + v0 + vc];
        t2[ur * 65 + vc] = __floats2half2_rn(v.x, v.y);
    }
    __syncthreads();
    for (int j = threadIdx.x; j < 64 * 64; j += blockDim.x) {
        int vr = j >> 6, lane = j & 63;
        int J = (int)(__brev((unsigned)lane) >> 26);
        smapsP[(size_t)((c * NXY + v0 + vr) * 5 + s5) * 64 + lane] = t2[J * 65 + vr];
    }
}

// X0[c*G+tc][p] = kspace[p][c] * mask[p][c][t0+tc] * (-1)^(m+n)   (half2)
__global__ __launch_bounds__(256) void k_prep_input(const float* __restrict__ ksr,
                                                    const float* __restrict__ ksi,
                                                    const float* __restrict__ mask,
                                                    __half2* __restrict__ X0,
                                                    int t0, int G) {
    const int Q = NC * G;
    const int QP = Q + 1;
    const int p0 = blockIdx.x * 16;
    __shared__ float s_mask[16 * 501];
    __shared__ float s_kr[16 * 21];
    __shared__ float s_ki[16 * 21];
    for (int j = threadIdx.x; j < 16 * NC; j += blockDim.x) {
        int p = j / NC, c = j - p * NC;
        s_kr[p * 21 + c] = ksr[(size_t)p0 * NC + j];
        s_ki[p * 21 + c] = ksi[(size_t)p0 * NC + j];
    }
    for (int j = threadIdx.x; j < 16 * Q; j += blockDim.x) {
        int p = j / Q, qq = j - p * Q;
        int c = qq / G, tc = qq - c * G;
        s_mask[p * QP + qq] =
            mask[(size_t)(p0 + p) * (NC * NT) + c * NT + (t0 + tc)];
    }
    __syncthreads();
    for (int j = threadIdx.x; j < 16 * Q; j += blockDim.x) {
        int p = j & 15, q = j >> 4;
        int c = q / G;
        int pg = p0 + p;
        int m = pg / NXY, n = pg - m * NXY;
        float sgn = ((m + n) & 1) ? -1.0f : 1.0f;
        float mk = s_mask[p * QP + q] * sgn;
        X0[(size_t)q * NPIX + pg] =
            __floats2half2_rn(s_kr[p * 21 + c] * mk, s_ki[p * 21 + c] * mk);
    }
}

// Row FFTs (over n) for one (c,tc); 16 rows per block; LDS transpose so
// Z[q][v][m] has m contiguous. All half2.
__global__ __launch_bounds__(256) void k_fft_rows(const __half2* __restrict__ X0,
                                                  __half2* __restrict__ Z, int G) {
    const int mtile = blockIdx.x;   // 0..19 (16 rows each)
    const int tc = blockIdx.y;
    const int c = blockIdx.z;
    const int q = c * G + tc;
    const int wave = threadIdx.x >> 6;
    const int lane = threadIdx.x & 63;
    const int m0 = mtile * 16;
    __shared__ __half2 tile[NXY * 17];  // [v][16 + 1 pad]
    Tw t;
    tw_init(t);
    const __half2* src = X0 + (size_t)q * NPIX;
    #pragma unroll
    for (int rnd = 0; rnd < 4; ++rnd) {
        int mm = rnd * 4 + wave;
        const __half2* row = src + (size_t)(m0 + mm) * NXY + lane * 5;
        float2 x[5], out[5];
        #pragma unroll
        for (int r = 0; r < 5; ++r) x[r] = __half22float2(row[r]);
        fft320(t, x, out);
        #pragma unroll
        for (int s5 = 0; s5 < 5; ++s5) {
            int v = t.J + 64 * s5;
            tile[v * 17 + mm] = __floats2half2_rn(out[s5].x, out[s5].y);
        }
    }
    __syncthreads();
    __half2* dst = Z + (size_t)q * NPIX + m0;
    for (int j = threadIdx.x; j < NXY * 16; j += blockDim.x) {
        int mm = j & 15, v = j >> 4;
        dst[(size_t)v * NXY + mm] = tile[v * 17 + mm];
    }
}

// Column FFTs (over m) + coil combine (coalesced smapsP), accumulate over c in
// fp32 regs. Block = (v-tile of 8, tc). Writes im_t[t][u][v] (float2).
__global__ __launch_bounds__(256) void k_fft_cols_combine(const __half2* __restrict__ Z,
                                                          const __half2* __restrict__ smapsP,
                                                          float2* __restrict__ imt,
                                                          int t0, int G) {
    const int vtile = blockIdx.x;   // 0..39
    const int tc = blockIdx.y;
    const int wave = threadIdx.x >> 6;
    const int lane = threadIdx.x & 63;
    const int v0 = vtile * 8;
    __shared__ float tile_x[NXY * 9];   // [u][8 v + 1 pad]
    __shared__ float tile_y[NXY * 9];
    Tw t;
    tw_init(t);
    float2 accA[5], accB[5];
    #pragma unroll
    for (int s5 = 0; s5 < 5; ++s5) {
        accA[s5] = make_float2(0.f, 0.f);
        accB[s5] = make_float2(0.f, 0.f);
    }
    const int vA = v0 + wave;
    const int vB = v0 + 4 + wave;
    for (int c = 0; c < NC; ++c) {
        const __half2* zc = Z + (size_t)(c * G + tc) * NPIX;
        {
            const __half2* col = zc + (size_t)vA * NXY + lane * 5;
            float2 x[5], out[5];
            #pragma unroll
            for (int r = 0; r < 5; ++r) x[r] = __half22float2(col[r]);
            fft320(t, x, out);
            const __half2* sp = smapsP + (size_t)((c * NXY + vA) * 5) * 64 + lane;
            #pragma unroll
            for (int s5 = 0; s5 < 5; ++s5) {
                float2 sm = __half22float2(sp[s5 * 64]);
                float2 tt = cmul(out[s5], sm);
                accA[s5].x += tt.x;
                accA[s5].y += tt.y;
            }
        }
        {
            const __half2* col = zc + (size_t)vB * NXY + lane * 5;
            float2 x[5], out[5];
            #pragma unroll
            for (int r = 0; r < 5; ++r) x[r] = __half22float2(col[r]);
            fft320(t, x, out);
            const __half2* sp = smapsP + (size_t)((c * NXY + vB) * 5) * 64 + lane;
            #pragma unroll
            for (int s5 = 0; s5 < 5; ++s5) {
                float2 sm = __half22float2(sp[s5 * 64]);
                float2 tt = cmul(out[s5], sm);
                accB[s5].x += tt.x;
                accB[s5].y += tt.y;
            }
        }
    }
    #pragma unroll
    for (int s5 = 0; s5 < 5; ++s5) {
        int u = t.J + 64 * s5;
        tile_x[u * 9 + wave] = accA[s5].x;
        tile_y[u * 9 + wave] = accA[s5].y;
        tile_x[u * 9 + 4 + wave] = accB[s5].x;
        tile_y[u * 9 + 4 + wave] = accB[s5].y;
    }
    __syncthreads();
    float2* dst = imt + (size_t)(t0 + tc) * NPIX + v0;
    for (int j = threadIdx.x; j < NXY * 8; j += blockDim.x) {
        int vv = j & 7, u = j >> 3;
        dst[(size_t)u * NXY + vv] = make_float2(tile_x[u * 9 + vv], tile_y[u * 9 + vv]);
    }
}

// Bilinear warp per motion state + sum over t. out = [2][320][320].
__global__ __launch_bounds__(256) void k_warp_sum(const float2* __restrict__ imt,
                                                  const float* __restrict__ flow,
                                                  float* __restrict__ out) {
    int p = blockIdx.x * blockDim.x + threadIdx.x;
    if (p >= NPIX) return;
    int x = p / NXY, y = p - x * NXY;
    float fx = (float)x, fy = (float)y;
    float ar = 0.f, ai = 0.f;
    const float* fl = flow + (size_t)p * (2 * NT);
    for (int t = 0; t < NT; ++t) {
        float u = fl[t];
        float v = fl[NT + t];
        float xs = fminf(fmaxf(fx + u, 0.0f), 319.0f);
        float ys = fminf(fmaxf(fy + v, 0.0f), 319.0f);
        float x0f = floorf(xs), y0f = floorf(ys);
        int x0 = (int)x0f, y0 = (int)y0f;
        int x1 = min(x0 + 1, NXY - 1), y1 = min(y0 + 1, NXY - 1);
        float wx = xs - x0f, wy = ys - y0f;
        const float2* base = imt + (size_t)t * NPIX;
        float2 c00 = base[x0 * NXY + y0];
        float2 c01 = base[x0 * NXY + y1];
        float2 c10 = base[x1 * NXY + y0];
        float2 c11 = base[x1 * NXY + y1];
        float w00 = (1.f - wx) * (1.f - wy), w01 = (1.f - wx) * wy;
        float w10 = wx * (1.f - wy), w11 = wx * wy;
        ar += c00.x * w00 + c01.x * w01 + c10.x * w10 + c11.x * w11;
        ai += c00.y * w00 + c01.y * w01 + c10.y * w10 + c11.y * w11;
    }
    out[p] = ar;
    out[NPIX + p] = ai;
}

extern "C" void kernel_launch(void* const* d_in, const int* in_sizes, int n_in,
                              void* d_out, int out_size, void* d_ws, size_t ws_size,
                              hipStream_t stream) {
    const float* ksr = (const float*)d_in[0];
    const float* ksi = (const float*)d_in[1];
    const float* mask = (const float*)d_in[2];
    const float* smr = (const float*)d_in[3];
    const float* smi = (const float*)d_in[4];
    const float* flow = (const float*)d_in[5];
    float* out = (float*)d_out;

    char* ws = (char*)d_ws;
    const size_t smapsC_bytes = (size_t)NC * NPIX * sizeof(float2);    // 16.4 MB
    const size_t smapsP_bytes = (size_t)NC * NPIX * 5 * 64 / NXY * sizeof(__half2); // == NC*NPIX*4
    const size_t imt_bytes = (size_t)NT * NPIX * sizeof(float2);       // 20.5 MB
    const size_t fixed = smapsC_bytes + smapsP_bytes + imt_bytes;
    const size_t per_t = (size_t)2 * NC * NPIX * sizeof(__half2);      // X0+Z per t: 16.4 MB

    int G = 1;
    if (ws_size > fixed + per_t) {
        size_t g = (ws_size - fixed) / per_t;
        G = (int)(g > (size_t)NT ? (size_t)NT : g);
    }
    if (G < 1) G = 1;

    float2* smapsC = (float2*)ws;
    __half2* smapsP = (__half2*)(ws + smapsC_bytes);
    float2* imt = (float2*)(ws + smapsC_bytes + smapsP_bytes);
    __half2* X0 = (__half2*)(ws + fixed);
    __half2* Z = (__half2*)(ws + fixed + (size_t)NC * G * NPIX * sizeof(__half2));

    k_prep_smaps<<<NPIX / 64, 256, 0, stream>>>(smr, smi, smapsC);
    k_perm_smaps<<<dim3(NC, 5, 5), 256, 0, stream>>>(smapsC, smapsP);
    for (int t0 = 0; t0 < NT; t0 += G) {
        int g = (NT - t0) < G ? (NT - t0) : G;
        k_prep_input<<<NPIX / 16, 256, 0, stream>>>(ksr, ksi, mask, X0, t0, g);
        k_fft_rows<<<dim3(20, g, NC), 256, 0, stream>>>(X0, Z, g);
        k_fft_cols_combine<<<dim3(40, g), 256, 0, stream>>>(Z, smapsP, imt, t0, g);
    }
    k_warp_sum<<<(NPIX + 255) / 256, 256, 0, stream>>>(imt, flow, out);
}

// Round 3
// 823.556 us; speedup vs baseline: 1.4079x; 1.0956x over previous
//
#include <hip/hip_runtime.h>
#include <hip/hip_fp16.h>
#include <math.h>

#define NXY 320
#define NC 20
#define NT 25
#define NPIX 102400   // 320*320
#define PI_F 3.14159265358979f
#define TWOPI_F 6.28318530717959f

__device__ __forceinline__ float2 cmul(float2 a, float2 b) {
    return make_float2(a.x * b.x - a.y * b.y, a.x * b.y + a.y * b.x);
}

// Per-lane FFT twiddles — invariant across every FFT a thread performs.
struct Tw {
    float2 st[6];   // stage twiddle: (1,0) lower half, e^{+i*pi*i/h} upper
    float  sgn[6];  // +1 lower, -1 upper
    float2 w5[5];   // w5[r] = e^{+2*pi*i * r*J / 320}
    int J;          // bitrev6(lane)
};

__device__ __forceinline__ void tw_init(Tw& t) {
    const int lane = threadIdx.x & 63;
    #pragma unroll
    for (int s = 0; s < 6; ++s) {
        const int h = 32 >> s;
        const bool up = (lane & h) != 0;
        t.sgn[s] = up ? -1.0f : 1.0f;
        if (up) {
            float ss, cc;
            __sincosf(PI_F * (float)(lane & (h - 1)) / (float)h, &ss, &cc);
            t.st[s] = make_float2(cc, ss);
        } else {
            t.st[s] = make_float2(1.0f, 0.0f);
        }
    }
    t.J = (int)(__brev((unsigned)lane) >> 26);
    t.w5[0] = make_float2(1.0f, 0.0f);
    #pragma unroll
    for (int r = 1; r < 5; ++r) {
        float ss, cc;
        __sincosf(TWOPI_F * (float)(r * t.J) / 320.0f, &ss, &cc);
        t.w5[r] = make_float2(cc, ss);
    }
}

// K interleaved 320-point DFTs (+i sign) by one wave.
// x[k][r] = seq_k[5*lane + r] in; out[k][s5] = X_k[J + 64*s5].
template <int K>
__device__ __forceinline__ void fft320xK(const Tw& t, float2 (&x)[K][5], float2 (&out)[K][5]) {
    #pragma unroll
    for (int s = 0; s < 6; ++s) {
        const int h = 32 >> s;
        #pragma unroll
        for (int r = 0; r < 5; ++r) {
            #pragma unroll
            for (int k = 0; k < K; ++k) {
                float ox = __shfl_xor(x[k][r].x, h);
                float oy = __shfl_xor(x[k][r].y, h);
                float dx = fmaf(t.sgn[s], x[k][r].x, ox);
                float dy = fmaf(t.sgn[s], x[k][r].y, oy);
                x[k][r].x = dx * t.st[s].x - dy * t.st[s].y;
                x[k][r].y = dx * t.st[s].y + dy * t.st[s].x;
            }
        }
    }
    const float W5x[5] = {1.0f, 0.309016994f, -0.809016994f, -0.809016994f, 0.309016994f};
    const float W5y[5] = {0.0f, 0.951056516f, 0.587785252f, -0.587785252f, -0.951056516f};
    #pragma unroll
    for (int k = 0; k < K; ++k) {
        float2 T[5];
        T[0] = x[k][0];
        #pragma unroll
        for (int r = 1; r < 5; ++r) T[r] = cmul(x[k][r], t.w5[r]);
        #pragma unroll
        for (int s5 = 0; s5 < 5; ++s5) {
            float2 acc = T[0];
            #pragma unroll
            for (int r = 1; r < 5; ++r) {
                const int kk = (r * s5) % 5;
                acc.x += T[r].x * W5x[kk] - T[r].y * W5y[kk];
                acc.y += T[r].x * W5y[kk] + T[r].y * W5x[kk];
            }
            out[k][s5] = acc;
        }
    }
}

// smapsC[c][p] = conj(smaps[p][c]) * (-1)^(m+n) / 320   (fp32 staging table)
__global__ __launch_bounds__(256) void k_prep_smaps(const float* __restrict__ smr,
                                                    const float* __restrict__ smi,
                                                    float2* __restrict__ smapsC) {
    const int p0 = blockIdx.x * 64;
    __shared__ float s_r[64 * 21];
    __shared__ float s_i[64 * 21];
    for (int j = threadIdx.x; j < 64 * NC; j += blockDim.x) {
        int p = j / NC, c = j - p * NC;
        s_r[p * 21 + c] = smr[(size_t)p0 * NC + j];
        s_i[p * 21 + c] = smi[(size_t)p0 * NC + j];
    }
    __syncthreads();
    for (int j = threadIdx.x; j < 64 * NC; j += blockDim.x) {
        int c = j >> 6, p = j & 63;
        int pg = p0 + p;
        int m = pg / NXY, n = pg - m * NXY;
        float sgn = (((m + n) & 1) ? -1.0f : 1.0f) * (1.0f / 320.0f);
        smapsC[(size_t)c * NPIX + pg] = make_float2(s_r[p * 21 + c] * sgn,
                                                    -s_i[p * 21 + c] * sgn);
    }
}

// smapsP[((c*320 + v)*5 + s5)*64 + lane] = smapsC[c][(bitrev6(lane)+64*s5)*320 + v] (half2)
__global__ __launch_bounds__(256) void k_perm_smaps(const float2* __restrict__ smapsC,
                                                    __half2* __restrict__ smapsP) {
    const int c = blockIdx.x;
    const int s5 = blockIdx.y;
    const int v0 = blockIdx.z * 64;
    __shared__ __half2 t2[64 * 65];
    for (int j = threadIdx.x; j < 64 * 64; j += blockDim.x) {
        int ur = j >> 6, vc = j & 63;
        float2 v = smapsC[(size_t)c * NPIX + (size_t)(s5 * 64 + ur) * NXY + v0 + vc];
        t2[ur * 65 + vc] = __floats2half2_rn(v.x, v.y);
    }
    __syncthreads();
    for (int j = threadIdx.x; j < 64 * 64; j += blockDim.x) {
        int vr = j >> 6, lane = j & 63;
        int J = (int)(__brev((unsigned)lane) >> 26);
        smapsP[(size_t)((c * NXY + v0 + vr) * 5 + s5) * 64 + lane] = t2[J * 65 + vr];
    }
}

// X0[c*G+tc][p] = kspace[p][c] * mask[p][c][t0+tc] * (-1)^(m+n)   (half2)
// Division-free inner loops; always stages the full 500-wide mask row block.
__global__ __launch_bounds__(256) void k_prep_input(const float* __restrict__ ksr,
                                                    const float* __restrict__ ksi,
                                                    const float* __restrict__ mask,
                                                    __half2* __restrict__ X0,
                                                    int t0, int G) {
    const int p0 = blockIdx.x * 16;
    __shared__ float s_mask[16 * 501];
    __shared__ float s_kr[16 * 21];
    __shared__ float s_ki[16 * 21];
    for (int j = threadIdx.x; j < 16 * NC; j += blockDim.x) {
        int p = j / NC, c = j - p * NC;     // compile-time divisor
        s_kr[p * 21 + c] = ksr[(size_t)p0 * NC + j];
        s_ki[p * 21 + c] = ksi[(size_t)p0 * NC + j];
    }
    for (int j = threadIdx.x; j < 16 * 500; j += blockDim.x) {
        int p = j / 500, col = j - p * 500; // compile-time divisor
        s_mask[p * 501 + col] = mask[(size_t)p0 * 500 + j];
    }
    __syncthreads();
    const int p = threadIdx.x & 15;
    const int g16 = threadIdx.x >> 4;
    const int pg = p0 + p;
    const int m = pg / NXY;
    const int n = pg - m * NXY;
    const float sgn = ((m + n) & 1) ? -1.0f : 1.0f;
    #pragma unroll
    for (int c = 0; c < NC; ++c) {
        const float kr = s_kr[p * 21 + c] * sgn;
        const float ki = s_ki[p * 21 + c] * sgn;
        for (int tc = g16; tc < G; tc += 16) {
            const int q = c * G + tc;
            const float mk = s_mask[p * 501 + c * NT + t0 + tc];
            X0[(size_t)q * NPIX + pg] = __floats2half2_rn(kr * mk, ki * mk);
        }
    }
}

// Row FFTs (over n): one block = 16 rows of one (c,tc); each wave does 4 rows
// interleaved (K=4 ILP). LDS transpose so Z[q][v][m] has m contiguous.
__global__ __launch_bounds__(256) void k_fft_rows(const __half2* __restrict__ X0,
                                                  __half2* __restrict__ Z, int G) {
    const int mtile = blockIdx.x;   // 0..19
    const int tc = blockIdx.y;
    const int c = blockIdx.z;
    const int q = c * G + tc;
    const int wave = threadIdx.x >> 6;
    const int lane = threadIdx.x & 63;
    const int m0 = mtile * 16;
    __shared__ __half2 tile[NXY * 17];  // [v][16 + 1 pad]
    Tw t;
    tw_init(t);
    const __half2* src = X0 + (size_t)q * NPIX;
    float2 x[4][5], out[4][5];
    #pragma unroll
    for (int k = 0; k < 4; ++k) {
        const __half2* row = src + (size_t)(m0 + wave + 4 * k) * NXY + lane * 5;
        #pragma unroll
        for (int r = 0; r < 5; ++r) x[k][r] = __half22float2(row[r]);
    }
    fft320xK<4>(t, x, out);
    #pragma unroll
    for (int k = 0; k < 4; ++k) {
        const int mm = wave + 4 * k;
        #pragma unroll
        for (int s5 = 0; s5 < 5; ++s5) {
            int v = t.J + 64 * s5;
            tile[v * 17 + mm] = __floats2half2_rn(out[k][s5].x, out[k][s5].y);
        }
    }
    __syncthreads();
    __half2* dst = Z + (size_t)q * NPIX + m0;
    for (int j = threadIdx.x; j < NXY * 16; j += blockDim.x) {
        int mm = j & 15, v = j >> 4;
        dst[(size_t)v * NXY + mm] = tile[v * 17 + mm];
    }
}

// Column FFTs (over m) + coil combine; K=2 ILP (two v's per wave), coils split
// across blockIdx.z (2 halves of 10), fp16 partial images imtP[half][t][u][v].
__global__ __launch_bounds__(256) void k_fft_cols_combine(const __half2* __restrict__ Z,
                                                          const __half2* __restrict__ smapsP,
                                                          __half2* __restrict__ imtP,
                                                          int t0, int G) {
    const int vtile = blockIdx.x;   // 0..39
    const int tc = blockIdx.y;
    const int half = blockIdx.z;    // 0/1 -> coils [10h, 10h+10)
    const int wave = threadIdx.x >> 6;
    const int lane = threadIdx.x & 63;
    const int v0 = vtile * 8;
    const int vA = v0 + wave;
    const int vB = v0 + 4 + wave;
    __shared__ __half2 tile[NXY * 9];   // [u][8 v + 1 pad]
    Tw t;
    tw_init(t);
    float2 acc[2][5];
    #pragma unroll
    for (int k = 0; k < 2; ++k)
        #pragma unroll
        for (int s5 = 0; s5 < 5; ++s5) acc[k][s5] = make_float2(0.f, 0.f);
    const int c0 = half * 10;
    for (int c = c0; c < c0 + 10; ++c) {
        const __half2* zc = Z + (size_t)(c * G + tc) * NPIX;
        float2 x[2][5], out[2][5];
        const __half2* colA = zc + (size_t)vA * NXY + lane * 5;
        const __half2* colB = zc + (size_t)vB * NXY + lane * 5;
        #pragma unroll
        for (int r = 0; r < 5; ++r) {
            x[0][r] = __half22float2(colA[r]);
            x[1][r] = __half22float2(colB[r]);
        }
        fft320xK<2>(t, x, out);
        const __half2* spA = smapsP + (size_t)((c * NXY + vA) * 5) * 64 + lane;
        const __half2* spB = smapsP + (size_t)((c * NXY + vB) * 5) * 64 + lane;
        #pragma unroll
        for (int s5 = 0; s5 < 5; ++s5) {
            float2 smA = __half22float2(spA[s5 * 64]);
            float2 smB = __half22float2(spB[s5 * 64]);
            float2 ta = cmul(out[0][s5], smA);
            float2 tb = cmul(out[1][s5], smB);
            acc[0][s5].x += ta.x; acc[0][s5].y += ta.y;
            acc[1][s5].x += tb.x; acc[1][s5].y += tb.y;
        }
    }
    #pragma unroll
    for (int s5 = 0; s5 < 5; ++s5) {
        int u = t.J + 64 * s5;
        tile[u * 9 + wave] = __floats2half2_rn(acc[0][s5].x, acc[0][s5].y);
        tile[u * 9 + 4 + wave] = __floats2half2_rn(acc[1][s5].x, acc[1][s5].y);
    }
    __syncthreads();
    __half2* dst = imtP + (size_t)(half * NT + t0 + tc) * NPIX + v0;
    for (int j = threadIdx.x; j < NXY * 8; j += blockDim.x) {
        int vv = j & 7, u = j >> 3;
        dst[(size_t)u * NXY + vv] = tile[u * 9 + vv];
    }
}

// Bilinear warp + sum over t; reduces the two coil-half partials.
// flow staged via LDS for coalesced reads.
__global__ __launch_bounds__(256) void k_warp_sum(const __half2* __restrict__ imtP,
                                                  const float* __restrict__ flow,
                                                  float* __restrict__ out) {
    const int p0 = blockIdx.x * 256;
    const int tid = threadIdx.x;
    __shared__ float s_fl[2 * NT * 257];
    for (int j = tid; j < 256 * 50; j += 256) {
        int pp = j / 50, rem = j - pp * 50;       // compile-time divisors
        int d = rem / 25, tt = rem - d * 25;
        s_fl[(d * NT + tt) * 257 + pp] = flow[(size_t)p0 * 50 + j];
    }
    __syncthreads();
    const int p = p0 + tid;
    const int x = p / NXY, y = p - x * NXY;
    const float fx = (float)x, fy = (float)y;
    float ar = 0.f, ai = 0.f;
    for (int t = 0; t < NT; ++t) {
        float u = s_fl[t * 257 + tid];
        float v = s_fl[(NT + t) * 257 + tid];
        float xs = fminf(fmaxf(fx + u, 0.0f), 319.0f);
        float ys = fminf(fmaxf(fy + v, 0.0f), 319.0f);
        float x0f = floorf(xs), y0f = floorf(ys);
        int x0 = (int)x0f, y0 = (int)y0f;
        int x1 = min(x0 + 1, NXY - 1), y1 = min(y0 + 1, NXY - 1);
        float wx = xs - x0f, wy = ys - y0f;
        const __half2* b0 = imtP + (size_t)t * NPIX;
        const __half2* b1 = imtP + (size_t)(NT + t) * NPIX;
        int i00 = x0 * NXY + y0, i01 = x0 * NXY + y1;
        int i10 = x1 * NXY + y0, i11 = x1 * NXY + y1;
        float2 c00 = __half22float2(b0[i00]); float2 d00 = __half22float2(b1[i00]);
        float2 c01 = __half22float2(b0[i01]); float2 d01 = __half22float2(b1[i01]);
        float2 c10 = __half22float2(b0[i10]); float2 d10 = __half22float2(b1[i10]);
        float2 c11 = __half22float2(b0[i11]); float2 d11 = __half22float2(b1[i11]);
        c00.x += d00.x; c00.y += d00.y;
        c01.x += d01.x; c01.y += d01.y;
        c10.x += d10.x; c10.y += d10.y;
        c11.x += d11.x; c11.y += d11.y;
        float w00 = (1.f - wx) * (1.f - wy), w01 = (1.f - wx) * wy;
        float w10 = wx * (1.f - wy), w11 = wx * wy;
        ar += c00.x * w00 + c01.x * w01 + c10.x * w10 + c11.x * w11;
        ai += c00.y * w00 + c01.y * w01 + c10.y * w10 + c11.y * w11;
    }
    out[p] = ar;
    out[NPIX + p] = ai;
}

extern "C" void kernel_launch(void* const* d_in, const int* in_sizes, int n_in,
                              void* d_out, int out_size, void* d_ws, size_t ws_size,
                              hipStream_t stream) {
    const float* ksr = (const float*)d_in[0];
    const float* ksi = (const float*)d_in[1];
    const float* mask = (const float*)d_in[2];
    const float* smr = (const float*)d_in[3];
    const float* smi = (const float*)d_in[4];
    const float* flow = (const float*)d_in[5];
    float* out = (float*)d_out;

    char* ws = (char*)d_ws;
    const size_t smapsC_bytes = (size_t)NC * NPIX * sizeof(float2);          // 16.4 MB
    const size_t smapsP_bytes = (size_t)NC * NPIX * sizeof(__half2);         // 8.2 MB
    const size_t imtP_bytes = (size_t)2 * NT * NPIX * sizeof(__half2);       // 20.5 MB
    const size_t fixed = smapsC_bytes + smapsP_bytes + imtP_bytes;
    const size_t per_t = (size_t)2 * NC * NPIX * sizeof(__half2);            // X0+Z: 16.4 MB

    int G = 1;
    if (ws_size > fixed + per_t) {
        size_t g = (ws_size - fixed) / per_t;
        G = (int)(g > (size_t)NT ? (size_t)NT : g);
    }
    if (G < 1) G = 1;

    float2* smapsC = (float2*)ws;
    __half2* smapsP = (__half2*)(ws + smapsC_bytes);
    __half2* imtP = (__half2*)(ws + smapsC_bytes + smapsP_bytes);
    __half2* X0 = (__half2*)(ws + fixed);
    __half2* Z = (__half2*)(ws + fixed + (size_t)NC * G * NPIX * sizeof(__half2));

    k_prep_smaps<<<NPIX / 64, 256, 0, stream>>>(smr, smi, smapsC);
    k_perm_smaps<<<dim3(NC, 5, 5), 256, 0, stream>>>(smapsC, smapsP);
    for (int t0 = 0; t0 < NT; t0 += G) {
        int g = (NT - t0) < G ? (NT - t0) : G;
        k_prep_input<<<NPIX / 16, 256, 0, stream>>>(ksr, ksi, mask, X0, t0, g);
        k_fft_rows<<<dim3(20, g, NC), 256, 0, stream>>>(X0, Z, g);
        k_fft_cols_combine<<<dim3(40, g, 2), 256, 0, stream>>>(Z, smapsP, imtP, t0, g);
    }
    k_warp_sum<<<NPIX / 256, 256, 0, stream>>>(imtP, flow, out);
}